// Round 10
// baseline (186.002 us; speedup 1.0000x reference)
//
#include <hip/hip_runtime.h>
#include <hip/hip_bf16.h>

// HMM forward, chunk-parallel + MFMA. B=64, T=4096, S=64.
//
// R10 change vs R9: replace the cooperative grid.sync with DECOUPLED
// LOOKBACK. R7/R9 failed with absmax 21120 = max|alpha_ref| -> output
// all zeros -> hipLaunchCooperativeKernel REJECTED the launch (512 blocks
// x 64KB LDS exceeds the runtime's co-residency accounting); the kernel
// never ran. Normal launches at 64KB LDS are proven (R3). The scan's
// dependency is only FORWARD in cg within a batch (block (b,cg) needs
// chunk-groups cg' <= cg, all at smaller blockIdx), so a grid barrier is
// overkill: after stage1 each block publishes its 16 warm/bound scalars,
// __threadfence(), release-stores a flag; before stage2 it acquire-spins
// on its <=7 predecessors (rocPRIM single-pass-scan pattern; waiters
// depend only on earlier-dispatched blocks). Flags zeroed per launch via
// stream-ordered hipMemsetAsync (graph-capturable). Unpublished ws reads
// feed only discarded scan lanes (prefix property). Everything else is
// byte-identical to R9 (incl. the R8 split-scan fix, untested until now).
//
// Structure: single fused kernel, normal launch.
//   stage1: R5 phaseA; bf16(v) history -> 64KB LDS tile (task-XOR column
//           swizzle, <=4-way banks). No global slab traffic.
//   stage2: per-wave shuffle-scan of the 128 boundary deltas (512B),
//           decode own LDS history, write 16 chunks = ONE contiguous
//           128KB span of out (fully coalesced). cg==7 block emits log_Z.
// XCD-aware blockIdx->(b,cg) map (all 8 blocks of a batch on one XCD).
//
// Linear-space recurrence (R4): v = 2^(alpha*log2e - 6s), Ahat=exp(T)*2^-6.
//   step: d[jt] = sum_kb mfma16(Ahat, pack_bf16(v)); v' = d * exp(emis)
//   phi = -150*ln2 for chunk 0 (exact t=0 anchor), else 0 (absorbed by
//   the per-chunk additive correction).
// Geometry: LL=32, C_CH=128, WARM=24, PF=8; warm s=1..24, main s=25..56.

#define BB 64
#define TT 4096
#define SS 64
#define C_CH 128
#define LL 32
#define WARM 24
#define PF 8

typedef __attribute__((ext_vector_type(4))) short bh4;
typedef __attribute__((ext_vector_type(4))) float f32x4;
typedef __attribute__((ext_vector_type(4))) unsigned short us4;

#define LOG2E 1.44269504088896340736f
#define LN2F  0.69314718055994530942f

__device__ __forceinline__ float fexp2(float x) {
#if __has_builtin(__builtin_amdgcn_exp2f)
    return __builtin_amdgcn_exp2f(x);
#else
    return exp2f(x);
#endif
}
__device__ __forceinline__ float flog2(float x) {
#if __has_builtin(__builtin_amdgcn_logf)
    return __builtin_amdgcn_logf(x);
#else
    return log2f(x);
#endif
}
__device__ __forceinline__ int pack_bf16(float x, float y) {
    __hip_bfloat162 h = __float22bfloat162_rn(make_float2(x, y));
    int r; __builtin_memcpy(&r, &h, 4); return r;
}
__device__ __forceinline__ float bf_to_f32(unsigned short u) {
    unsigned int w = ((unsigned int)u) << 16;
    float f; __builtin_memcpy(&f, &w, 4); return f;
}
union PB2 { int i[2]; bh4 v; us4 u; };

__device__ __forceinline__ f32x4 mfma16(bh4 a, bh4 b, f32x4 c) {
#if __has_builtin(__builtin_amdgcn_mfma_f32_16x16x16bf16_1k)
    return __builtin_amdgcn_mfma_f32_16x16x16bf16_1k(a, b, c, 0, 0, 0);
#else
    asm("v_mfma_f32_16x16x16_bf16 %0, %1, %2, %0" : "+v"(c) : "v"(a), "v"(b));
    return c;
#endif
}

// One linear-space recurrence step for 16 tasks.
//   vv[kb] holds v[task=lane&15][j = 16*kb + 4q + r]  (B-layout == D-layout)
//   eE[jt] = exp(emis_row[j]) elementwise (2^-6 folded into Af).
__device__ __forceinline__ void do_step(f32x4 (&vv)[4], const f32x4 (&eE)[4],
                                        const bh4 (&Af)[4][4]) {
    bh4 Bf[4];
    #pragma unroll
    for (int kb = 0; kb < 4; ++kb) {
        PB2 pb;
        pb.i[0] = pack_bf16(vv[kb].x, vv[kb].y);
        pb.i[1] = pack_bf16(vv[kb].z, vv[kb].w);
        Bf[kb] = pb.v;
    }
    #pragma unroll
    for (int jt = 0; jt < 4; ++jt) {
        f32x4 d0 = {0.f, 0.f, 0.f, 0.f};
        f32x4 d1 = {0.f, 0.f, 0.f, 0.f};
        d0 = mfma16(Af[jt][0], Bf[0], d0);
        d1 = mfma16(Af[jt][1], Bf[1], d1);
        d0 = mfma16(Af[jt][2], Bf[2], d0);
        d1 = mfma16(Af[jt][3], Bf[3], d1);
        f32x4 d = d0 + d1;
        vv[jt] = d * eE[jt];
    }
}

__device__ __forceinline__ void load_row(f32x4 (&dst)[4],
                                         const float* __restrict__ eb,
                                         int t, int off) {
    const float* p = eb + (t & (TT - 1)) * SS + off;
    #pragma unroll
    for (int jt = 0; jt < 4; ++jt)
        dst[jt] = *(const f32x4*)(p + 16 * jt);
}

__global__ __launch_bounds__(64)
__attribute__((amdgpu_waves_per_eu(1, 1)))
void hmm_fused(const float* __restrict__ trans,
               const float* __restrict__ emis,
               float* __restrict__ out,
               float* __restrict__ ws_warm,
               float* __restrict__ ws_bound,
               int* __restrict__ flags) {
    // 64KB history: [task 16][row 32][col 64] bf16, columns stored in 8B
    // units u=0..15 at u^task (<=4-way banks on write and read).
    __shared__ unsigned short hist[32768];

    const int lane = threadIdx.x;
    const int n = lane & 15, q = lane >> 4;
    const int w = blockIdx.x;                  // 0..511
    // XCD-aware map: xcd = w&7 serves batches b with b>>3 == w&7.
    const int b  = 8 * (w & 7) + ((w >> 3) & 7);
    const int cg = w >> 6;                     // 0..7
    const int c = 16 * cg + n;                 // this lane's task (0..127)
    const bool is_c0 = (c == 0);
    const int off = 4 * q;

    // A-fragments (K=16): A_jt,kb[m=n][k=4q+e] = exp(T[16kb+4q+e][16jt+n])
    // with the constant per-step rescale 2^-6 folded in.
    bh4 Af[4][4];
    #pragma unroll
    for (int jt = 0; jt < 4; ++jt)
        #pragma unroll
        for (int kb = 0; kb < 4; ++kb) {
            float v0 = __expf(trans[(16 * kb + 4 * q + 0) * SS + 16 * jt + n]) * 0.015625f;
            float v1 = __expf(trans[(16 * kb + 4 * q + 1) * SS + 16 * jt + n]) * 0.015625f;
            float v2 = __expf(trans[(16 * kb + 4 * q + 2) * SS + 16 * jt + n]) * 0.015625f;
            float v3 = __expf(trans[(16 * kb + 4 * q + 3) * SS + 16 * jt + n]) * 0.015625f;
            PB2 pb;
            pb.i[0] = pack_bf16(v0, v1);
            pb.i[1] = pack_bf16(v2, v3);
            Af[jt][kb] = pb.v;
        }

    const float* eb = emis + (size_t)b * TT * SS;

    const int t0 = LL * c - (WARM + 1);        // per-lane; c=0 => -25

    // phi = -150*ln2 for chunk 0 so its t=0 anchor is EXACT.
    const float cL = is_c0 ? (-150.0f * LN2F) : 0.0f;

    // Init: v = exp(emis[t0]) (pseudo; garbage-warm for c=0), plus the
    // true alpha0 row pre-exped for the c0 override.
    f32x4 vv[4], e0v[4], ebuf[PF][4];
    {
        f32x4 a0[4], z0[4];
        load_row(a0, eb, t0, off);
        load_row(z0, eb, 0, off);
        #pragma unroll
        for (int jt = 0; jt < 4; ++jt) {
            vv[jt].x = fexp2(a0[jt].x * LOG2E);
            vv[jt].y = fexp2(a0[jt].y * LOG2E);
            vv[jt].z = fexp2(a0[jt].z * LOG2E);
            vv[jt].w = fexp2(a0[jt].w * LOG2E);
            e0v[jt].x = fexp2(z0[jt].x * LOG2E);
            e0v[jt].y = fexp2(z0[jt].y * LOG2E);
            e0v[jt].z = fexp2(z0[jt].z * LOG2E);
            e0v[jt].w = fexp2(z0[jt].w * LOG2E);
        }
    }
    #pragma unroll
    for (int k = 0; k < PF; ++k) load_row(ebuf[k], eb, t0 + 1 + k, off);

    // Warm-up: s = 1..24 (3 groups of PF=8), no stores, no log path.
    #pragma unroll 1
    for (int g = 0; g < 3; ++g) {
        #pragma unroll
        for (int k = 0; k < PF; ++k) {
            int s = PF * g + k + 1;
            f32x4 eE[4];
            #pragma unroll
            for (int jt = 0; jt < 4; ++jt) {
                eE[jt].x = fexp2(ebuf[k][jt].x * LOG2E);
                eE[jt].y = fexp2(ebuf[k][jt].y * LOG2E);
                eE[jt].z = fexp2(ebuf[k][jt].z * LOG2E);
                eE[jt].w = fexp2(ebuf[k][jt].w * LOG2E);
            }
            load_row(ebuf[k], eb, t0 + s + PF, off);
            do_step(vv, eE, Af);
        }
    }
    // Boundary (uncorrected) alpha at t = 32c-1 (s=24): lane n holds j=0.
    if (lane < 16)
        ws_warm[b * C_CH + 16 * cg + lane] =
            fmaf(flog2(vv[0].x), LN2F, 144.0f * LN2F + cL);

    // Main: s = 25..56; store bf16(v) row (s-25) into LDS hist.
    #pragma unroll 1
    for (int g = 0; g < 4; ++g) {
        #pragma unroll
        for (int k = 0; k < PF; ++k) {
            int s = WARM + 1 + PF * g + k;
            f32x4 eE[4];
            #pragma unroll
            for (int jt = 0; jt < 4; ++jt) {
                eE[jt].x = fexp2(ebuf[k][jt].x * LOG2E);
                eE[jt].y = fexp2(ebuf[k][jt].y * LOG2E);
                eE[jt].z = fexp2(ebuf[k][jt].z * LOG2E);
                eE[jt].w = fexp2(ebuf[k][jt].w * LOG2E);
            }
            load_row(ebuf[k], eb, t0 + s + PF, off);
            do_step(vv, eE, Af);
            if (k == 0 && g == 0 && is_c0) {
                // chunk 0: replace garbage warm result with true alpha0
                // (phi = -150*ln2 makes the decoded value exactly emis[0]).
                #pragma unroll
                for (int jt = 0; jt < 4; ++jt) vv[jt] = e0v[jt];
            }
            unsigned short* wp = hist + (n * 32 + (s - (WARM + 1))) * 64;
            #pragma unroll
            for (int kb = 0; kb < 4; ++kb) {
                PB2 pb;
                pb.i[0] = pack_bf16(vv[kb].x, vv[kb].y);
                pb.i[1] = pack_bf16(vv[kb].z, vv[kb].w);
                *(us4*)(wp + ((((kb << 2) + q) ^ n) << 2)) = pb.u;
            }
        }
    }
    if (lane < 16)
        ws_bound[b * C_CH + 16 * cg + lane] =
            fmaf(flog2(vv[0].x), LN2F, 336.0f * LN2F + cL);

    // ---- publish + decoupled lookback (replaces grid.sync) ---------------
    __threadfence();                            // make ws_warm/ws_bound visible
    if (lane == 0)
        __hip_atomic_store(&flags[8 * b + cg], 1,
                           __ATOMIC_RELEASE, __HIP_MEMORY_SCOPE_AGENT);
    // Wait for predecessors of this batch (all at SMALLER blockIdx).
    for (int p = 0; p < cg; ++p) {
        while (__hip_atomic_load(&flags[8 * b + p],
                                 __ATOMIC_ACQUIRE, __HIP_MEMORY_SCOPE_AGENT) == 0)
            __builtin_amdgcn_s_sleep(8);
    }
    __threadfence();

    // ---- stage 2: per-wave redundant scan + decode + coalesced writes ----
    // delta[c] = prefix_{c'<=c} (bound[c'-1] - warm[c']), d[0]=0.
    // Unpublished high chunks (cg'>cg) feed only discarded scan lanes
    // (prefix at index i depends only on inputs <= i).
    const float* wwp = ws_warm + b * C_CH;
    const float* wbp = ws_bound + b * C_CH;
    float dlo = 0.f;
    if (lane > 0) dlo = wbp[lane - 1] - wwp[lane];
    float dhi = wbp[63 + lane] - wwp[64 + lane];
    #pragma unroll
    for (int o2 = 1; o2 < 64; o2 <<= 1) {
        float v = __shfl_up(dlo, o2, 64);
        if (lane >= o2) dlo += v;
    }
    // Inclusive-scan dhi FIRST, then add the low-half total once (R8 fix).
    #pragma unroll
    for (int o2 = 1; o2 < 64; o2 <<= 1) {
        float v = __shfl_up(dhi, o2, 64);
        if (lane >= o2) dhi += v;
    }
    dhi += __shfl(dlo, 63, 64);

    // Decode: wave's 16 chunks cover t = 512*cg .. 512*cg+511 of batch b
    // -> one contiguous 128KB span. 1KB per store instruction.
    float* obase = out + (size_t)b * TT * SS + (size_t)(512 * cg) * SS;
    const int lhi = lane >> 4, llo = lane & 15;
    #pragma unroll 1
    for (int nn = 0; nn < 16; ++nn) {
        const int chunk = 16 * cg + nn;
        const float dn = (chunk < 64) ? __shfl(dlo, chunk, 64)
                                      : __shfl(dhi, chunk - 64, 64);
        const float base_cs = (chunk == 0 ? -150.0f * LN2F : 0.0f) + dn;
        #pragma unroll
        for (int ii = 0; ii < 8; ++ii) {
            const int r = ii * 4 + lhi;
            const us4 u0 = *(const us4*)&hist[nn * 2048 + r * 64 +
                                             ((llo ^ nn) << 2)];
            const float cs = fmaf(6.0f * (float)(r + 25), LN2F, base_cs);
            f32x4 a;
            a.x = fmaf(flog2(bf_to_f32(u0[0])), LN2F, cs);
            a.y = fmaf(flog2(bf_to_f32(u0[1])), LN2F, cs);
            a.z = fmaf(flog2(bf_to_f32(u0[2])), LN2F, cs);
            a.w = fmaf(flog2(bf_to_f32(u0[3])), LN2F, cs);
            *(f32x4*)(obase + nn * 2048 + ii * 256 + lhi * 64 + llo * 4) = a;
        }
    }

    // log_Z from the corrected last row (chunk 127, row 31) — cg==7 blocks.
    if (cg == 7) {
        const float d127 = __shfl(dhi, 63, 64);
        const unsigned short hv =
            hist[15 * 2048 + 31 * 64 + (((lane >> 2) ^ 15) << 2) + (lane & 3)];
        float a = fmaf(flog2(bf_to_f32(hv)), LN2F, 336.0f * LN2F + d127);
        float mx = a;
        #pragma unroll
        for (int o2 = 32; o2 >= 1; o2 >>= 1)
            mx = fmaxf(mx, __shfl_xor(mx, o2, 64));
        float sv = __expf(a - mx);
        #pragma unroll
        for (int o2 = 32; o2 >= 1; o2 >>= 1)
            sv += __shfl_xor(sv, o2, 64);
        if (lane == 0)
            out[(size_t)BB * TT * SS + b] = mx + __logf(sv);
    }
}

extern "C" void kernel_launch(void* const* d_in, const int* in_sizes, int n_in,
                              void* d_out, int out_size, void* d_ws, size_t ws_size,
                              hipStream_t stream) {
    const float* trans = (const float*)d_in[0];   // (S,S)
    const float* emis  = (const float*)d_in[1];   // (B,T,S)
    // d_in[2] = seq_lens — unused by the reference.
    float* out = (float*)d_out;                   // alpha (B,T,S) ++ log_Z (B,)

    float* ws_warm  = (float*)d_ws;               // B*C floats
    float* ws_bound = ws_warm + BB * C_CH;        // B*C floats
    int*   flags    = (int*)(ws_bound + BB * C_CH);  // B*8 ints

    hipMemsetAsync(flags, 0, BB * 8 * sizeof(int), stream);
    hmm_fused<<<dim3(BB * 8), dim3(64), 0, stream>>>(trans, emis, out,
                                                     ws_warm, ws_bound, flags);
}